// Round 14
// baseline (300.236 us; speedup 1.0000x reference)
//
#include <hip/hip_runtime.h>
#include <hip/hip_cooperative_groups.h>
#include <math.h>

namespace cg = cooperative_groups;

static constexpr int NN  = 8192;     // nodes
static constexpr int EE  = 262144;   // edges
static constexpr int IND = 512;      // input feature dim
static constexpr int HH1 = 256;
static constexpr int RCAP = 128;     // padded per-row edge capacity (max deg ~56)

typedef _Float16 f16x8  __attribute__((ext_vector_type(8)));
typedef _Float16 f16x4  __attribute__((ext_vector_type(4)));
typedef _Float16 f16x2  __attribute__((ext_vector_type(2)));
typedef float    f32x4  __attribute__((ext_vector_type(4)));

static __device__ __forceinline__ float fast_sigmoid(float x) {
    float e = __expf(-x);
    return __builtin_amdgcn_rcpf(1.f + e);
}

// One cooperative kernel: 256 blocks x 512 threads (1 block/CU -> co-residency guaranteed
// for any VGPR<=256/wave, LDS 12.7KB). Phase math element-identical to the R12 pipeline.
__global__ __launch_bounds__(512) void k_mega(const int* __restrict__ erow,
                                              const int* __restrict__ ecol,
                                              const float* __restrict__ eval,
                                              const float* __restrict__ X,
                                              const float* __restrict__ W1,
                                              const float* __restrict__ b1,
                                              const float* __restrict__ W2,
                                              const float* __restrict__ b2,
                                              const float* __restrict__ W3,
                                              const float* __restrict__ b3,
                                              const float* __restrict__ noise,
                                              float* __restrict__ adj,
                                              float* __restrict__ zout,
                                              int* __restrict__ cnt,
                                              int2* __restrict__ epack,
                                              _Float16* __restrict__ W1T,
                                              _Float16* __restrict__ W23T,
                                              _Float16* __restrict__ zh,
                                              _Float16* __restrict__ sup1h,
                                              _Float16* __restrict__ s23h) {
    cg::grid_group grid = cg::this_grid();
    __shared__ float tile[32][33];
    __shared__ _Float16 hs[16][264];

    const int bid = blockIdx.x;
    const int tid = threadIdx.x;
    const int w = tid >> 6, l = tid & 63;
    const int lr = l & 15, kg = l >> 4;

    // ---------------- P0: zero cnt (blocks 0..15) + W1T (16..143) + W23T (144..175) -----------
    if (bid < 16) {
        cnt[bid * 512 + tid] = 0;
    } else if (bid < 176) {
        bool act = tid < 256;
        int c = tid & 31;
        int r0 = (tid >> 5) & 7;
        if (bid < 144) {
            int t = bid - 16;
            int tk = t >> 3, tn = t & 7;
            if (act) {
#pragma unroll
                for (int i = 0; i < 4; i++) {
                    int r = r0 * 4 + i;
                    tile[r][c] = W1[(tk * 32 + r) * HH1 + tn * 32 + c];
                }
            }
            __syncthreads();
            if (act) {
#pragma unroll
                for (int i = 0; i < 4; i++) {
                    int rr = r0 * 4 + i;
                    W1T[(tn * 32 + rr) * IND + tk * 32 + c] = (_Float16)tile[c][rr];
                }
            }
        } else {
            int t = bid - 144;
            int tk = t >> 2, tn = t & 3;
            const float* Wsrc = (tn < 2) ? W2 : W3;
            int nc0 = (tn & 1) * 32;
            if (act) {
#pragma unroll
                for (int i = 0; i < 4; i++) {
                    int r = r0 * 4 + i;
                    tile[r][c] = Wsrc[(tk * 32 + r) * 64 + nc0 + c];
                }
            }
            __syncthreads();
            if (act) {
#pragma unroll
                for (int i = 0; i < 4; i++) {
                    int rr = r0 * 4 + i;
                    W23T[(tn * 32 + rr) * HH1 + tk * 32 + c] = (_Float16)tile[c][rr];
                }
            }
        }
    }
    grid.sync();

    // ---------------- P1: gemm1 BM=32,BN=256 (8 waves: 2x4) + scatter (2 chunks of 512) -------
    {
        int wm = w >> 2, wn = w & 3;
        int row0 = bid * 32 + wm * 16;
        int col0 = wn * 64;

        f32x4 acc[4];
#pragma unroll
        for (int nt = 0; nt < 4; nt++) acc[nt] = (f32x4){0.f, 0.f, 0.f, 0.f};

        for (int ks = 0; ks < IND; ks += 32) {
            int ko = ks + kg * 8;
            const float* xp = &X[(size_t)(row0 + lr) * IND + ko];
            float4 x0 = *(const float4*)xp;
            float4 x1 = *(const float4*)(xp + 4);
            f16x8 a = {(_Float16)x0.x, (_Float16)x0.y, (_Float16)x0.z, (_Float16)x0.w,
                       (_Float16)x1.x, (_Float16)x1.y, (_Float16)x1.z, (_Float16)x1.w};
            f16x8 bb[4];
#pragma unroll
            for (int nt = 0; nt < 4; nt++)
                bb[nt] = *(const f16x8*)&W1T[(size_t)(col0 + nt * 16 + lr) * IND + ko];
#pragma unroll
            for (int nt = 0; nt < 4; nt++)
                acc[nt] = __builtin_amdgcn_mfma_f32_16x16x32_f16(a, bb[nt], acc[nt], 0, 0, 0);
        }
#pragma unroll
        for (int nt = 0; nt < 4; nt++)
#pragma unroll
            for (int r = 0; r < 4; r++)
                sup1h[(size_t)(row0 + kg * 4 + r) * HH1 + col0 + nt * 16 + lr] = (_Float16)acc[nt][r];

#pragma unroll
        for (int j = 0; j < 2; j++) {
            int e = (bid * 2 + j) * 512 + tid;
            int r = erow[e];
            int pos = atomicAdd(&cnt[r], 1);
            epack[(size_t)r * RCAP + pos] = make_int2(ecol[e], __float_as_int(eval[e]));
        }
    }
    grid.sync();

    // ---------------- P2: fused SpMM1 + GEMM23 (R12 structure, 2 row-group iterations) --------
    for (int j = 0; j < 2; j++) {
        if (j) __syncthreads();   // previous iteration's gemm23 reads of hs complete
        int brow0 = (bid + 256 * j) * 16;
#pragma unroll
        for (int rr = 0; rr < 2; rr++) {
            int rloc = w * 2 + rr;
            int row = brow0 + rloc;
            int s = row * RCAP, eend = s + cnt[row];
            float4 acc = make_float4(0.f, 0.f, 0.f, 0.f);
            int i = s;
            for (; i + 4 <= eend; i += 4) {
                int2 p0 = epack[i];
                int2 p1 = epack[i + 1];
                int2 p2 = epack[i + 2];
                int2 p3 = epack[i + 3];
                f16x4 t0 = *(const f16x4*)&sup1h[(size_t)p0.x * HH1 + l * 4];
                f16x4 t1 = *(const f16x4*)&sup1h[(size_t)p1.x * HH1 + l * 4];
                f16x4 t2 = *(const f16x4*)&sup1h[(size_t)p2.x * HH1 + l * 4];
                f16x4 t3 = *(const f16x4*)&sup1h[(size_t)p3.x * HH1 + l * 4];
                float v0 = __int_as_float(p0.y), v1 = __int_as_float(p1.y);
                float v2 = __int_as_float(p2.y), v3 = __int_as_float(p3.y);
                acc.x += v0 * (float)t0[0] + v1 * (float)t1[0] + v2 * (float)t2[0] + v3 * (float)t3[0];
                acc.y += v0 * (float)t0[1] + v1 * (float)t1[1] + v2 * (float)t2[1] + v3 * (float)t3[1];
                acc.z += v0 * (float)t0[2] + v1 * (float)t1[2] + v2 * (float)t2[2] + v3 * (float)t3[2];
                acc.w += v0 * (float)t0[3] + v1 * (float)t1[3] + v2 * (float)t2[3] + v3 * (float)t3[3];
            }
            for (; i < eend; i++) {
                int2 p0 = epack[i];
                f16x4 t0 = *(const f16x4*)&sup1h[(size_t)p0.x * HH1 + l * 4];
                float v0 = __int_as_float(p0.y);
                acc.x += v0 * (float)t0[0];
                acc.y += v0 * (float)t0[1];
                acc.z += v0 * (float)t0[2];
                acc.w += v0 * (float)t0[3];
            }
            float4 bb = ((const float4*)b1)[l];
            f16x4 o;
            o[0] = (_Float16)tanhf(acc.x + bb.x);
            o[1] = (_Float16)tanhf(acc.y + bb.y);
            o[2] = (_Float16)tanhf(acc.z + bb.z);
            o[3] = (_Float16)tanhf(acc.w + bb.w);
            *(f16x4*)&hs[rloc][l * 4] = o;
        }
        __syncthreads();

        int colbase = w * 16;
        f32x4 acc = (f32x4){0.f, 0.f, 0.f, 0.f};
        for (int ks = 0; ks < HH1; ks += 32) {
            int ko = ks + kg * 8;
            f16x8 a = *(const f16x8*)&hs[lr][ko];
            f16x8 bfrag = *(const f16x8*)&W23T[(size_t)(colbase + lr) * HH1 + ko];
            acc = __builtin_amdgcn_mfma_f32_16x16x32_f16(a, bfrag, acc, 0, 0, 0);
        }
#pragma unroll
        for (int r = 0; r < 4; r++)
            s23h[(size_t)(brow0 + kg * 4 + r) * 128 + colbase + lr] = (_Float16)acc[r];
    }
    grid.sync();

    // ---------------- P3: SpMM2+3 + reparameterization (1 row/wave, 8 rows/block-iter) --------
#pragma unroll 1
    for (int j = 0; j < 4; j++) {
        int row = (bid + 256 * j) * 8 + w;
        int s = row * RCAP, eend = s + cnt[row];
        float ax = 0.f, ay = 0.f;
        int i = s;
        for (; i + 4 <= eend; i += 4) {
            int2 p0 = epack[i];
            int2 p1 = epack[i + 1];
            int2 p2 = epack[i + 2];
            int2 p3 = epack[i + 3];
            f16x2 t0 = *(const f16x2*)&s23h[(size_t)p0.x * 128 + l * 2];
            f16x2 t1 = *(const f16x2*)&s23h[(size_t)p1.x * 128 + l * 2];
            f16x2 t2 = *(const f16x2*)&s23h[(size_t)p2.x * 128 + l * 2];
            f16x2 t3 = *(const f16x2*)&s23h[(size_t)p3.x * 128 + l * 2];
            float v0 = __int_as_float(p0.y), v1 = __int_as_float(p1.y);
            float v2 = __int_as_float(p2.y), v3 = __int_as_float(p3.y);
            ax += v0 * (float)t0[0] + v1 * (float)t1[0] + v2 * (float)t2[0] + v3 * (float)t3[0];
            ay += v0 * (float)t0[1] + v1 * (float)t1[1] + v2 * (float)t2[1] + v3 * (float)t3[1];
        }
        for (; i < eend; i++) {
            int2 p0 = epack[i];
            f16x2 t0 = *(const f16x2*)&s23h[(size_t)p0.x * 128 + l * 2];
            float v0 = __int_as_float(p0.y);
            ax += v0 * (float)t0[0];
            ay += v0 * (float)t0[1];
        }
        float bx, by;
        if (l < 32) { bx = b2[2 * l]; by = b2[2 * l + 1]; }
        else        { bx = b3[2 * (l - 32)]; by = b3[2 * (l - 32) + 1]; }
        float t0 = tanhf(ax + bx);
        float t1 = tanhf(ay + by);
        float u0 = __shfl_xor(t0, 32, 64);
        float u1 = __shfl_xor(t1, 32, 64);
        if (l < 32) {
            float2 nz = ((const float2*)noise)[(size_t)row * 32 + l];
            float z0 = t0 + nz.x * __expf(u0);
            float z1 = t1 + nz.y * __expf(u1);
            ((float2*)zout)[(size_t)row * 32 + l] = make_float2(z0, z1);
            *(f16x2*)&zh[(size_t)row * 64 + l * 2] = (f16x2){(_Float16)z0, (_Float16)z1};
        }
    }
    grid.sync();

    // ---------------- P4: adj = sigmoid(z z^T); 2 wave-groups x 8 vtiles per block ------------
    {
        int g = w >> 2, wl = w & 3;
#pragma unroll 1
        for (int j = 0; j < 8; j++) {
            int vb = bid + 256 * (2 * j + g);       // 0..4095 unique
            int bi = vb >> 6, bj = vb & 63;
            const int i0 = bi * 128 + wl * 32;
            const int j0 = bj * 128;

            f16x8 a[2][2];
#pragma unroll
            for (int mt = 0; mt < 2; mt++)
#pragma unroll
                for (int kk = 0; kk < 2; kk++)
                    a[mt][kk] = *(const f16x8*)&zh[(size_t)(i0 + mt * 16 + lr) * 64 + kk * 32 + kg * 8];

            f32x4 acc[2][8];
#pragma unroll
            for (int mt = 0; mt < 2; mt++)
#pragma unroll
                for (int nt = 0; nt < 8; nt++)
                    acc[mt][nt] = (f32x4){0.f, 0.f, 0.f, 0.f};

#pragma unroll
            for (int nt = 0; nt < 8; nt++) {
                f16x8 b0 = *(const f16x8*)&zh[(size_t)(j0 + nt * 16 + lr) * 64 + 0  + kg * 8];
                f16x8 b1 = *(const f16x8*)&zh[(size_t)(j0 + nt * 16 + lr) * 64 + 32 + kg * 8];
                acc[0][nt] = __builtin_amdgcn_mfma_f32_16x16x32_f16(a[0][0], b0, acc[0][nt], 0, 0, 0);
                acc[0][nt] = __builtin_amdgcn_mfma_f32_16x16x32_f16(a[0][1], b1, acc[0][nt], 0, 0, 0);
                acc[1][nt] = __builtin_amdgcn_mfma_f32_16x16x32_f16(a[1][0], b0, acc[1][nt], 0, 0, 0);
                acc[1][nt] = __builtin_amdgcn_mfma_f32_16x16x32_f16(a[1][1], b1, acc[1][nt], 0, 0, 0);
            }

#pragma unroll
            for (int nt = 0; nt < 8; nt++) {
#pragma unroll
                for (int mt = 0; mt < 2; mt++) {
                    size_t orow = (size_t)(j0 + nt * 16 + lr);
                    size_t ocol = (size_t)(i0 + mt * 16 + kg * 4);
                    float4 o;
                    o.x = fast_sigmoid(acc[mt][nt][0]);
                    o.y = fast_sigmoid(acc[mt][nt][1]);
                    o.z = fast_sigmoid(acc[mt][nt][2]);
                    o.w = fast_sigmoid(acc[mt][nt][3]);
                    *(float4*)&adj[orow * NN + ocol] = o;
                }
            }
        }
    }
}

extern "C" void kernel_launch(void* const* d_in, const int* in_sizes, int n_in,
                              void* d_out, int out_size, void* d_ws, size_t ws_size,
                              hipStream_t stream) {
    const int*   erow  = (const int*)d_in[0];
    const int*   ecol  = (const int*)d_in[1];
    const float* eval  = (const float*)d_in[2];
    const float* X     = (const float*)d_in[3];
    const float* W1    = (const float*)d_in[4];
    const float* b1    = (const float*)d_in[5];
    const float* W2    = (const float*)d_in[6];
    const float* b2    = (const float*)d_in[7];
    const float* W3    = (const float*)d_in[8];
    const float* b3    = (const float*)d_in[9];
    const float* noise = (const float*)d_in[10];

    float* adj  = (float*)d_out;
    float* zout = (float*)d_out + (size_t)NN * NN;

    // scratch in d_ws (~9.8 MB)
    char* ws = (char*)d_ws;
    int*  cnt       = (int*)(ws + 0);                    // 32 KiB
    int2* epack     = (int2*)(ws + 32768);               // 8 MiB (padded rows)
    _Float16* W1T   = (_Float16*)(ws + 8421376);         // 256 KiB
    _Float16* W23T  = (_Float16*)(ws + 8683520);         // 64 KiB
    _Float16* zh    = (_Float16*)(ws + 8749056);         // 1 MiB

    // large temporaries in the adj region of d_out (fully overwritten by P4 last)
    char* ob = (char*)d_out;
    _Float16* sup1h = (_Float16*)(ob + 0);               // 4 MiB
    _Float16* s23h  = (_Float16*)(ob + 4194304);         // 2 MiB

    void* args[] = {
        (void*)&erow, (void*)&ecol, (void*)&eval, (void*)&X, (void*)&W1, (void*)&b1,
        (void*)&W2, (void*)&b2, (void*)&W3, (void*)&b3, (void*)&noise,
        (void*)&adj, (void*)&zout, (void*)&cnt, (void*)&epack,
        (void*)&W1T, (void*)&W23T, (void*)&zh, (void*)&sup1h, (void*)&s23h
    };
    hipLaunchCooperativeKernel((const void*)k_mega, dim3(256), dim3(512), args, 0, stream);
}

// Round 15
// 142.144 us; speedup vs baseline: 2.1122x; 2.1122x over previous
//
#include <hip/hip_runtime.h>
#include <math.h>

static constexpr int NN  = 8192;     // nodes
static constexpr int EE  = 262144;   // edges
static constexpr int IND = 512;      // input feature dim
static constexpr int HH1 = 256;
static constexpr int RCAP = 128;     // padded per-row edge capacity (max deg ~56)

typedef _Float16 f16x8  __attribute__((ext_vector_type(8)));
typedef _Float16 f16x4  __attribute__((ext_vector_type(4)));
typedef _Float16 f16x2  __attribute__((ext_vector_type(2)));
typedef float    f32x4  __attribute__((ext_vector_type(4)));

static __device__ __forceinline__ float fast_sigmoid(float x) {
    float e = __expf(-x);
    return __builtin_amdgcn_rcpf(1.f + e);
}

// ---------------- K0: init = zero cnt (blocks 0..31) + W1T (32..159) + W23T (160..191) ----------
__global__ __launch_bounds__(256) void k_init(const float* __restrict__ W1,
                                              const float* __restrict__ W2,
                                              const float* __restrict__ W3,
                                              _Float16* __restrict__ W1T,
                                              _Float16* __restrict__ W23T,
                                              int* __restrict__ cnt) {
    int b = blockIdx.x;
    if (b < 32) {
        cnt[b * 256 + threadIdx.x] = 0;
        return;
    }
    __shared__ float tile[32][33];
    int c = threadIdx.x & 31;
    int r0 = threadIdx.x >> 5;   // 0..7
    if (b < 160) {
        // W1 [512][256] -> W1T [256][512]
        int t = b - 32;
        int tk = t >> 3;   // 0..15
        int tn = t & 7;    // 0..7
#pragma unroll
        for (int i = 0; i < 4; i++) {
            int r = r0 * 4 + i;
            tile[r][c] = W1[(tk * 32 + r) * HH1 + tn * 32 + c];
        }
        __syncthreads();
#pragma unroll
        for (int i = 0; i < 4; i++) {
            int rr = r0 * 4 + i;
            W1T[(tn * 32 + rr) * IND + tk * 32 + c] = (_Float16)tile[c][rr];
        }
    } else {
        // [W2|W3] [256][64]x2 -> W23T [128][256]
        int t = b - 160;   // 0..31
        int tk = t >> 2;   // 0..7
        int tn = t & 3;    // tn<2 -> W2, else W3
        const float* Wsrc = (tn < 2) ? W2 : W3;
        int nc0 = (tn & 1) * 32;
#pragma unroll
        for (int i = 0; i < 4; i++) {
            int r = r0 * 4 + i;
            tile[r][c] = Wsrc[(tk * 32 + r) * 64 + nc0 + c];
        }
        __syncthreads();
#pragma unroll
        for (int i = 0; i < 4; i++) {
            int rr = r0 * 4 + i;
            W23T[(tn * 32 + rr) * HH1 + tk * 32 + c] = (_Float16)tile[c][rr];
        }
    }
}

// ---------------- K1: gemm1 (blocks 0..511) ∥ padded scatter (blocks 512..1535) ----------------
// gemm1: sup1h = fp16(X @ W1); X fp32 converted in-register. BM=32, BN=128, 4 waves 2x2.
__global__ __launch_bounds__(256) void k_gemm1_scatter(const float* __restrict__ X,
                                                       const _Float16* __restrict__ B,
                                                       _Float16* __restrict__ out,
                                                       const int* __restrict__ erow,
                                                       const int* __restrict__ ecol,
                                                       const float* __restrict__ eval,
                                                       int* __restrict__ cnt,
                                                       int2* __restrict__ epack) {
    int b = blockIdx.x;
    if (b >= 512) {
        int e = (b - 512) * 256 + threadIdx.x;
        int r = erow[e];
        int pos = atomicAdd(&cnt[r], 1);
        epack[(size_t)r * RCAP + pos] = make_int2(ecol[e], __float_as_int(eval[e]));
        return;
    }
    int bm = b >> 1, bn = b & 1;
    int w = threadIdx.x >> 6, l = threadIdx.x & 63;
    int wm = w >> 1, wn = w & 1;
    int lr = l & 15, kg = l >> 4;
    int row0 = bm * 32 + wm * 16;
    int col0 = bn * 128 + wn * 64;

    f32x4 acc[4];
#pragma unroll
    for (int nt = 0; nt < 4; nt++) acc[nt] = (f32x4){0.f, 0.f, 0.f, 0.f};

    for (int ks = 0; ks < IND; ks += 32) {
        int ko = ks + kg * 8;
        const float* xp = &X[(size_t)(row0 + lr) * IND + ko];
        float4 x0 = *(const float4*)xp;
        float4 x1 = *(const float4*)(xp + 4);
        f16x8 a = {(_Float16)x0.x, (_Float16)x0.y, (_Float16)x0.z, (_Float16)x0.w,
                   (_Float16)x1.x, (_Float16)x1.y, (_Float16)x1.z, (_Float16)x1.w};
        f16x8 bb[4];
#pragma unroll
        for (int nt = 0; nt < 4; nt++)
            bb[nt] = *(const f16x8*)&B[(size_t)(col0 + nt * 16 + lr) * IND + ko];
#pragma unroll
        for (int nt = 0; nt < 4; nt++)
            acc[nt] = __builtin_amdgcn_mfma_f32_16x16x32_f16(a, bb[nt], acc[nt], 0, 0, 0);
    }
#pragma unroll
    for (int nt = 0; nt < 4; nt++)
#pragma unroll
        for (int r = 0; r < 4; r++)
            out[(size_t)(row0 + kg * 4 + r) * HH1 + col0 + nt * 16 + lr] = (_Float16)acc[nt][r];
}

// ---------------- K2: fused SpMM1 + GEMM23: s23h = fp16( tanh(A@sup1h + b1) @ [W2|W3] ) -------
// 512 blocks x 512 threads (8 waves). Wave w aggregates rows 2w, 2w+1, tanh staged in LDS
// [16][264] fp16, then each wave does 8 MFMAs for a 16-col slice of s23.
__global__ __launch_bounds__(512) void k_spmm1_gemm23(const int* __restrict__ cnt,
                                                      const int2* __restrict__ epack,
                                                      const _Float16* __restrict__ sup,
                                                      const float* __restrict__ b1,
                                                      const _Float16* __restrict__ W23T,
                                                      _Float16* __restrict__ s23h) {
    __shared__ _Float16 hs[16][264];
    int w = threadIdx.x >> 6, l = threadIdx.x & 63;
    int brow0 = blockIdx.x * 16;

#pragma unroll
    for (int rr = 0; rr < 2; rr++) {
        int rloc = w * 2 + rr;
        int row = brow0 + rloc;
        int s = row * RCAP, eend = s + cnt[row];
        float4 acc = make_float4(0.f, 0.f, 0.f, 0.f);
        int i = s;
        for (; i + 4 <= eend; i += 4) {
            int2 p0 = epack[i];
            int2 p1 = epack[i + 1];
            int2 p2 = epack[i + 2];
            int2 p3 = epack[i + 3];
            f16x4 t0 = *(const f16x4*)&sup[(size_t)p0.x * HH1 + l * 4];
            f16x4 t1 = *(const f16x4*)&sup[(size_t)p1.x * HH1 + l * 4];
            f16x4 t2 = *(const f16x4*)&sup[(size_t)p2.x * HH1 + l * 4];
            f16x4 t3 = *(const f16x4*)&sup[(size_t)p3.x * HH1 + l * 4];
            float v0 = __int_as_float(p0.y), v1 = __int_as_float(p1.y);
            float v2 = __int_as_float(p2.y), v3 = __int_as_float(p3.y);
            acc.x += v0 * (float)t0[0] + v1 * (float)t1[0] + v2 * (float)t2[0] + v3 * (float)t3[0];
            acc.y += v0 * (float)t0[1] + v1 * (float)t1[1] + v2 * (float)t2[1] + v3 * (float)t3[1];
            acc.z += v0 * (float)t0[2] + v1 * (float)t1[2] + v2 * (float)t2[2] + v3 * (float)t3[2];
            acc.w += v0 * (float)t0[3] + v1 * (float)t1[3] + v2 * (float)t2[3] + v3 * (float)t3[3];
        }
        for (; i < eend; i++) {
            int2 p0 = epack[i];
            f16x4 t0 = *(const f16x4*)&sup[(size_t)p0.x * HH1 + l * 4];
            float v0 = __int_as_float(p0.y);
            acc.x += v0 * (float)t0[0];
            acc.y += v0 * (float)t0[1];
            acc.z += v0 * (float)t0[2];
            acc.w += v0 * (float)t0[3];
        }
        float4 bb = ((const float4*)b1)[l];
        f16x4 o;
        o[0] = (_Float16)tanhf(acc.x + bb.x);
        o[1] = (_Float16)tanhf(acc.y + bb.y);
        o[2] = (_Float16)tanhf(acc.z + bb.z);
        o[3] = (_Float16)tanhf(acc.w + bb.w);
        *(f16x4*)&hs[rloc][l * 4] = o;
    }
    __syncthreads();

    // GEMM23 phase: wave w -> s23 cols [16w, 16w+16), rows [brow0, brow0+16)
    int lr = l & 15, kg = l >> 4;
    int colbase = w * 16;
    f32x4 acc = (f32x4){0.f, 0.f, 0.f, 0.f};
    for (int ks = 0; ks < HH1; ks += 32) {
        int ko = ks + kg * 8;
        f16x8 a = *(const f16x8*)&hs[lr][ko];
        f16x8 bfrag = *(const f16x8*)&W23T[(size_t)(colbase + lr) * HH1 + ko];
        acc = __builtin_amdgcn_mfma_f32_16x16x32_f16(a, bfrag, acc, 0, 0, 0);
    }
#pragma unroll
    for (int r = 0; r < 4; r++)
        s23h[(size_t)(brow0 + kg * 4 + r) * 128 + colbase + lr] = (_Float16)acc[r];
}

// ---------------- K3: SpMM2+3 + reparameterization -> zout fp32, zh fp16 ----------------
__global__ __launch_bounds__(256) void k_spmm23v(const int* __restrict__ cnt,
                                                 const int2* __restrict__ epack,
                                                 const _Float16* __restrict__ s23,
                                                 const float* __restrict__ b2,
                                                 const float* __restrict__ b3,
                                                 const float* __restrict__ noise,
                                                 float* __restrict__ zout,
                                                 _Float16* __restrict__ zh) {
    int w = threadIdx.x >> 6, l = threadIdx.x & 63;
    int row = blockIdx.x * 4 + w;
    int s = row * RCAP, eend = s + cnt[row];
    float ax = 0.f, ay = 0.f;
    int i = s;
    for (; i + 4 <= eend; i += 4) {
        int2 p0 = epack[i];
        int2 p1 = epack[i + 1];
        int2 p2 = epack[i + 2];
        int2 p3 = epack[i + 3];
        f16x2 t0 = *(const f16x2*)&s23[(size_t)p0.x * 128 + l * 2];
        f16x2 t1 = *(const f16x2*)&s23[(size_t)p1.x * 128 + l * 2];
        f16x2 t2 = *(const f16x2*)&s23[(size_t)p2.x * 128 + l * 2];
        f16x2 t3 = *(const f16x2*)&s23[(size_t)p3.x * 128 + l * 2];
        float v0 = __int_as_float(p0.y), v1 = __int_as_float(p1.y);
        float v2 = __int_as_float(p2.y), v3 = __int_as_float(p3.y);
        ax += v0 * (float)t0[0] + v1 * (float)t1[0] + v2 * (float)t2[0] + v3 * (float)t3[0];
        ay += v0 * (float)t0[1] + v1 * (float)t1[1] + v2 * (float)t2[1] + v3 * (float)t3[1];
    }
    for (; i < eend; i++) {
        int2 p0 = epack[i];
        f16x2 t0 = *(const f16x2*)&s23[(size_t)p0.x * 128 + l * 2];
        float v0 = __int_as_float(p0.y);
        ax += v0 * (float)t0[0];
        ay += v0 * (float)t0[1];
    }
    float bx, by;
    if (l < 32) { bx = b2[2 * l]; by = b2[2 * l + 1]; }
    else        { bx = b3[2 * (l - 32)]; by = b3[2 * (l - 32) + 1]; }
    float t0 = tanhf(ax + bx);
    float t1 = tanhf(ay + by);
    float u0 = __shfl_xor(t0, 32, 64);   // mean lanes receive log_std partner
    float u1 = __shfl_xor(t1, 32, 64);
    if (l < 32) {
        float2 nz = ((const float2*)noise)[(size_t)row * 32 + l];
        float z0 = t0 + nz.x * __expf(u0);
        float z1 = t1 + nz.y * __expf(u1);
        ((float2*)zout)[(size_t)row * 32 + l] = make_float2(z0, z1);
        *(f16x2*)&zh[(size_t)row * 64 + l * 2] = (f16x2){(_Float16)z0, (_Float16)z1};
    }
}

// ---------------- K4: adj = sigmoid(z @ z^T), MFMA f16, transposed float4 stores ----------------
// adj symmetric: block (bi,bj) computes rows [bi*128+w*32,+32) x cols [bj*128,+128) and writes
// the TRANSPOSE (entry (p,q) written exactly once, by block bi=q/128, bj=p/128).
__global__ __launch_bounds__(256) void k_zzt_mfma(const _Float16* __restrict__ zh,
                                                  float* __restrict__ adj) {
    int bi = blockIdx.y, bj = blockIdx.x;
    int tid = threadIdx.x;
    int w = tid >> 6, l = tid & 63;
    int lr = l & 15, kg = l >> 4;
    const int i0 = bi * 128 + w * 32;
    const int j0 = bj * 128;

    f16x8 a[2][2];
#pragma unroll
    for (int mt = 0; mt < 2; mt++)
#pragma unroll
        for (int kk = 0; kk < 2; kk++)
            a[mt][kk] = *(const f16x8*)&zh[(size_t)(i0 + mt * 16 + lr) * 64 + kk * 32 + kg * 8];

    f32x4 acc[2][8];
#pragma unroll
    for (int mt = 0; mt < 2; mt++)
#pragma unroll
        for (int nt = 0; nt < 8; nt++)
            acc[mt][nt] = (f32x4){0.f, 0.f, 0.f, 0.f};

#pragma unroll
    for (int nt = 0; nt < 8; nt++) {
        f16x8 b0 = *(const f16x8*)&zh[(size_t)(j0 + nt * 16 + lr) * 64 + 0  + kg * 8];
        f16x8 b1 = *(const f16x8*)&zh[(size_t)(j0 + nt * 16 + lr) * 64 + 32 + kg * 8];
        acc[0][nt] = __builtin_amdgcn_mfma_f32_16x16x32_f16(a[0][0], b0, acc[0][nt], 0, 0, 0);
        acc[0][nt] = __builtin_amdgcn_mfma_f32_16x16x32_f16(a[0][1], b1, acc[0][nt], 0, 0, 0);
        acc[1][nt] = __builtin_amdgcn_mfma_f32_16x16x32_f16(a[1][0], b0, acc[1][nt], 0, 0, 0);
        acc[1][nt] = __builtin_amdgcn_mfma_f32_16x16x32_f16(a[1][1], b1, acc[1][nt], 0, 0, 0);
    }

#pragma unroll
    for (int nt = 0; nt < 8; nt++) {
#pragma unroll
        for (int mt = 0; mt < 2; mt++) {
            size_t orow = (size_t)(j0 + nt * 16 + lr);
            size_t ocol = (size_t)(i0 + mt * 16 + kg * 4);
            float4 o;
            o.x = fast_sigmoid(acc[mt][nt][0]);
            o.y = fast_sigmoid(acc[mt][nt][1]);
            o.z = fast_sigmoid(acc[mt][nt][2]);
            o.w = fast_sigmoid(acc[mt][nt][3]);
            *(float4*)&adj[orow * NN + ocol] = o;
        }
    }
}

extern "C" void kernel_launch(void* const* d_in, const int* in_sizes, int n_in,
                              void* d_out, int out_size, void* d_ws, size_t ws_size,
                              hipStream_t stream) {
    const int*   erow  = (const int*)d_in[0];
    const int*   ecol  = (const int*)d_in[1];
    const float* eval  = (const float*)d_in[2];
    const float* X     = (const float*)d_in[3];
    const float* W1    = (const float*)d_in[4];
    const float* b1    = (const float*)d_in[5];
    const float* W2    = (const float*)d_in[6];
    const float* b2    = (const float*)d_in[7];
    const float* W3    = (const float*)d_in[8];
    const float* b3    = (const float*)d_in[9];
    const float* noise = (const float*)d_in[10];

    float* adj  = (float*)d_out;
    float* zout = (float*)d_out + (size_t)NN * NN;

    // scratch in d_ws (~9.8 MB)
    char* ws = (char*)d_ws;
    int*  cnt       = (int*)(ws + 0);                    // 32 KiB
    int2* epack     = (int2*)(ws + 32768);               // 8 MiB (padded rows)
    _Float16* W1T   = (_Float16*)(ws + 8421376);         // 256 KiB
    _Float16* W23T  = (_Float16*)(ws + 8683520);         // 64 KiB
    _Float16* zh    = (_Float16*)(ws + 8749056);         // 1 MiB

    // large temporaries in the adj region of d_out (fully overwritten by k_zzt last)
    char* ob = (char*)d_out;
    _Float16* sup1h = (_Float16*)(ob + 0);               // 4 MiB
    _Float16* s23h  = (_Float16*)(ob + 4194304);         // 2 MiB

    k_init<<<192, 256, 0, stream>>>(W1, W2, W3, W1T, W23T, cnt);
    k_gemm1_scatter<<<512 + EE / 256, 256, 0, stream>>>(X, W1T, sup1h,
                                                        erow, ecol, eval, cnt, epack);
    k_spmm1_gemm23<<<512, 512, 0, stream>>>(cnt, epack, sup1h, b1, W23T, s23h);
    k_spmm23v<<<NN / 4, 256, 0, stream>>>(cnt, epack, s23h, b2, b3, noise, zout, zh);
    k_zzt_mfma<<<dim3(64, 64), 256, 0, stream>>>(zh, adj);
}

// Round 16
// 141.659 us; speedup vs baseline: 2.1194x; 1.0034x over previous
//
#include <hip/hip_runtime.h>
#include <math.h>

static constexpr int NN  = 8192;     // nodes
static constexpr int EE  = 262144;   // edges
static constexpr int IND = 512;      // input feature dim
static constexpr int HH1 = 256;
static constexpr int RCAP = 128;     // padded per-row edge capacity (max deg ~56)

typedef _Float16 f16x8  __attribute__((ext_vector_type(8)));
typedef _Float16 f16x4  __attribute__((ext_vector_type(4)));
typedef _Float16 f16x2  __attribute__((ext_vector_type(2)));
typedef float    f32x4  __attribute__((ext_vector_type(4)));

static __device__ __forceinline__ float fast_sigmoid(float x) {
    float e = __expf(-x);
    return __builtin_amdgcn_rcpf(1.f + e);
}

// ---------------- K0: init = zero cnt (blocks 0..31) + W1T (32..159) + W23T (160..191) ----------
__global__ __launch_bounds__(256) void k_init(const float* __restrict__ W1,
                                              const float* __restrict__ W2,
                                              const float* __restrict__ W3,
                                              _Float16* __restrict__ W1T,
                                              _Float16* __restrict__ W23T,
                                              int* __restrict__ cnt) {
    int b = blockIdx.x;
    if (b < 32) {
        cnt[b * 256 + threadIdx.x] = 0;
        return;
    }
    __shared__ float tile[32][33];
    int c = threadIdx.x & 31;
    int r0 = threadIdx.x >> 5;   // 0..7
    if (b < 160) {
        // W1 [512][256] -> W1T [256][512]
        int t = b - 32;
        int tk = t >> 3;   // 0..15
        int tn = t & 7;    // 0..7
#pragma unroll
        for (int i = 0; i < 4; i++) {
            int r = r0 * 4 + i;
            tile[r][c] = W1[(tk * 32 + r) * HH1 + tn * 32 + c];
        }
        __syncthreads();
#pragma unroll
        for (int i = 0; i < 4; i++) {
            int rr = r0 * 4 + i;
            W1T[(tn * 32 + rr) * IND + tk * 32 + c] = (_Float16)tile[c][rr];
        }
    } else {
        // [W2|W3] [256][64]x2 -> W23T [128][256]
        int t = b - 160;   // 0..31
        int tk = t >> 2;   // 0..7
        int tn = t & 3;    // tn<2 -> W2, else W3
        const float* Wsrc = (tn < 2) ? W2 : W3;
        int nc0 = (tn & 1) * 32;
#pragma unroll
        for (int i = 0; i < 4; i++) {
            int r = r0 * 4 + i;
            tile[r][c] = Wsrc[(tk * 32 + r) * 64 + nc0 + c];
        }
        __syncthreads();
#pragma unroll
        for (int i = 0; i < 4; i++) {
            int rr = r0 * 4 + i;
            W23T[(tn * 32 + rr) * HH1 + tk * 32 + c] = (_Float16)tile[c][rr];
        }
    }
}

// ---------------- K1: gemm1 (blocks 0..511) ∥ padded scatter (blocks 512..1535) ----------------
// gemm1: sup1h = fp16(X @ W1); X fp32 converted in-register. BM=32, BN=128, 4 waves 2x2.
__global__ __launch_bounds__(256) void k_gemm1_scatter(const float* __restrict__ X,
                                                       const _Float16* __restrict__ B,
                                                       _Float16* __restrict__ out,
                                                       const int* __restrict__ erow,
                                                       const int* __restrict__ ecol,
                                                       const float* __restrict__ eval,
                                                       int* __restrict__ cnt,
                                                       int2* __restrict__ epack) {
    int b = blockIdx.x;
    if (b >= 512) {
        int e = (b - 512) * 256 + threadIdx.x;
        int r = erow[e];
        int pos = atomicAdd(&cnt[r], 1);
        epack[(size_t)r * RCAP + pos] = make_int2(ecol[e], __float_as_int(eval[e]));
        return;
    }
    int bm = b >> 1, bn = b & 1;
    int w = threadIdx.x >> 6, l = threadIdx.x & 63;
    int wm = w >> 1, wn = w & 1;
    int lr = l & 15, kg = l >> 4;
    int row0 = bm * 32 + wm * 16;
    int col0 = bn * 128 + wn * 64;

    f32x4 acc[4];
#pragma unroll
    for (int nt = 0; nt < 4; nt++) acc[nt] = (f32x4){0.f, 0.f, 0.f, 0.f};

    for (int ks = 0; ks < IND; ks += 32) {
        int ko = ks + kg * 8;
        const float* xp = &X[(size_t)(row0 + lr) * IND + ko];
        float4 x0 = *(const float4*)xp;
        float4 x1 = *(const float4*)(xp + 4);
        f16x8 a = {(_Float16)x0.x, (_Float16)x0.y, (_Float16)x0.z, (_Float16)x0.w,
                   (_Float16)x1.x, (_Float16)x1.y, (_Float16)x1.z, (_Float16)x1.w};
        f16x8 bb[4];
#pragma unroll
        for (int nt = 0; nt < 4; nt++)
            bb[nt] = *(const f16x8*)&B[(size_t)(col0 + nt * 16 + lr) * IND + ko];
#pragma unroll
        for (int nt = 0; nt < 4; nt++)
            acc[nt] = __builtin_amdgcn_mfma_f32_16x16x32_f16(a, bb[nt], acc[nt], 0, 0, 0);
    }
#pragma unroll
    for (int nt = 0; nt < 4; nt++)
#pragma unroll
        for (int r = 0; r < 4; r++)
            out[(size_t)(row0 + kg * 4 + r) * HH1 + col0 + nt * 16 + lr] = (_Float16)acc[nt][r];
}

// ---------------- K2: fused SpMM1 + GEMM23, joint 2-row gather (8 gathers in flight) ----------
// 512 blocks x 512 threads (8 waves). Wave w aggregates rows 2w and 2w+1 TOGETHER: a joint
// 4-edge loop over min(len0,len1) issues 8 independent gathers/iter (2x the MLP of serial),
// then per-row tails. Per-row edge order unchanged. tanh -> LDS [16][264] -> MFMA -> s23h.
__global__ __launch_bounds__(512) void k_spmm1_gemm23(const int* __restrict__ cnt,
                                                      const int2* __restrict__ epack,
                                                      const _Float16* __restrict__ sup,
                                                      const float* __restrict__ b1,
                                                      const _Float16* __restrict__ W23T,
                                                      _Float16* __restrict__ s23h) {
    __shared__ _Float16 hs[16][264];
    int w = threadIdx.x >> 6, l = threadIdx.x & 63;
    int brow0 = blockIdx.x * 16;

    int rowA = brow0 + w * 2;
    int rowB = rowA + 1;
    int sA = rowA * RCAP, lenA = cnt[rowA];
    int sB = rowB * RCAP, lenB = cnt[rowB];
    float4 accA = make_float4(0.f, 0.f, 0.f, 0.f);
    float4 accB = make_float4(0.f, 0.f, 0.f, 0.f);

    int joint = (lenA < lenB) ? lenA : lenB;
    int i = 0;
    for (; i + 4 <= joint; i += 4) {
        int2 a0 = epack[sA + i],     a1 = epack[sA + i + 1];
        int2 a2 = epack[sA + i + 2], a3 = epack[sA + i + 3];
        int2 c0 = epack[sB + i],     c1 = epack[sB + i + 1];
        int2 c2 = epack[sB + i + 2], c3 = epack[sB + i + 3];
        f16x4 ta0 = *(const f16x4*)&sup[(size_t)a0.x * HH1 + l * 4];
        f16x4 ta1 = *(const f16x4*)&sup[(size_t)a1.x * HH1 + l * 4];
        f16x4 ta2 = *(const f16x4*)&sup[(size_t)a2.x * HH1 + l * 4];
        f16x4 ta3 = *(const f16x4*)&sup[(size_t)a3.x * HH1 + l * 4];
        f16x4 tb0 = *(const f16x4*)&sup[(size_t)c0.x * HH1 + l * 4];
        f16x4 tb1 = *(const f16x4*)&sup[(size_t)c1.x * HH1 + l * 4];
        f16x4 tb2 = *(const f16x4*)&sup[(size_t)c2.x * HH1 + l * 4];
        f16x4 tb3 = *(const f16x4*)&sup[(size_t)c3.x * HH1 + l * 4];
        float va0 = __int_as_float(a0.y), va1 = __int_as_float(a1.y);
        float va2 = __int_as_float(a2.y), va3 = __int_as_float(a3.y);
        float vb0 = __int_as_float(c0.y), vb1 = __int_as_float(c1.y);
        float vb2 = __int_as_float(c2.y), vb3 = __int_as_float(c3.y);
        accA.x += va0 * (float)ta0[0] + va1 * (float)ta1[0] + va2 * (float)ta2[0] + va3 * (float)ta3[0];
        accA.y += va0 * (float)ta0[1] + va1 * (float)ta1[1] + va2 * (float)ta2[1] + va3 * (float)ta3[1];
        accA.z += va0 * (float)ta0[2] + va1 * (float)ta1[2] + va2 * (float)ta2[2] + va3 * (float)ta3[2];
        accA.w += va0 * (float)ta0[3] + va1 * (float)ta1[3] + va2 * (float)ta2[3] + va3 * (float)ta3[3];
        accB.x += vb0 * (float)tb0[0] + vb1 * (float)tb1[0] + vb2 * (float)tb2[0] + vb3 * (float)tb3[0];
        accB.y += vb0 * (float)tb0[1] + vb1 * (float)tb1[1] + vb2 * (float)tb2[1] + vb3 * (float)tb3[1];
        accB.z += vb0 * (float)tb0[2] + vb1 * (float)tb1[2] + vb2 * (float)tb2[2] + vb3 * (float)tb3[2];
        accB.w += vb0 * (float)tb0[3] + vb1 * (float)tb1[3] + vb2 * (float)tb2[3] + vb3 * (float)tb3[3];
    }
    // row A tail
    {
        int ia = i;
        for (; ia + 4 <= lenA; ia += 4) {
            int2 a0 = epack[sA + ia],     a1 = epack[sA + ia + 1];
            int2 a2 = epack[sA + ia + 2], a3 = epack[sA + ia + 3];
            f16x4 t0 = *(const f16x4*)&sup[(size_t)a0.x * HH1 + l * 4];
            f16x4 t1 = *(const f16x4*)&sup[(size_t)a1.x * HH1 + l * 4];
            f16x4 t2 = *(const f16x4*)&sup[(size_t)a2.x * HH1 + l * 4];
            f16x4 t3 = *(const f16x4*)&sup[(size_t)a3.x * HH1 + l * 4];
            float v0 = __int_as_float(a0.y), v1 = __int_as_float(a1.y);
            float v2 = __int_as_float(a2.y), v3 = __int_as_float(a3.y);
            accA.x += v0 * (float)t0[0] + v1 * (float)t1[0] + v2 * (float)t2[0] + v3 * (float)t3[0];
            accA.y += v0 * (float)t0[1] + v1 * (float)t1[1] + v2 * (float)t2[1] + v3 * (float)t3[1];
            accA.z += v0 * (float)t0[2] + v1 * (float)t1[2] + v2 * (float)t2[2] + v3 * (float)t3[2];
            accA.w += v0 * (float)t0[3] + v1 * (float)t1[3] + v2 * (float)t2[3] + v3 * (float)t3[3];
        }
        for (; ia < lenA; ia++) {
            int2 p0 = epack[sA + ia];
            f16x4 t0 = *(const f16x4*)&sup[(size_t)p0.x * HH1 + l * 4];
            float v0 = __int_as_float(p0.y);
            accA.x += v0 * (float)t0[0];
            accA.y += v0 * (float)t0[1];
            accA.z += v0 * (float)t0[2];
            accA.w += v0 * (float)t0[3];
        }
    }
    // row B tail
    {
        int ib = i;
        for (; ib + 4 <= lenB; ib += 4) {
            int2 a0 = epack[sB + ib],     a1 = epack[sB + ib + 1];
            int2 a2 = epack[sB + ib + 2], a3 = epack[sB + ib + 3];
            f16x4 t0 = *(const f16x4*)&sup[(size_t)a0.x * HH1 + l * 4];
            f16x4 t1 = *(const f16x4*)&sup[(size_t)a1.x * HH1 + l * 4];
            f16x4 t2 = *(const f16x4*)&sup[(size_t)a2.x * HH1 + l * 4];
            f16x4 t3 = *(const f16x4*)&sup[(size_t)a3.x * HH1 + l * 4];
            float v0 = __int_as_float(a0.y), v1 = __int_as_float(a1.y);
            float v2 = __int_as_float(a2.y), v3 = __int_as_float(a3.y);
            accB.x += v0 * (float)t0[0] + v1 * (float)t1[0] + v2 * (float)t2[0] + v3 * (float)t3[0];
            accB.y += v0 * (float)t0[1] + v1 * (float)t1[1] + v2 * (float)t2[1] + v3 * (float)t3[1];
            accB.z += v0 * (float)t0[2] + v1 * (float)t1[2] + v2 * (float)t2[2] + v3 * (float)t3[2];
            accB.w += v0 * (float)t0[3] + v1 * (float)t1[3] + v2 * (float)t2[3] + v3 * (float)t3[3];
        }
        for (; ib < lenB; ib++) {
            int2 p0 = epack[sB + ib];
            f16x4 t0 = *(const f16x4*)&sup[(size_t)p0.x * HH1 + l * 4];
            float v0 = __int_as_float(p0.y);
            accB.x += v0 * (float)t0[0];
            accB.y += v0 * (float)t0[1];
            accB.z += v0 * (float)t0[2];
            accB.w += v0 * (float)t0[3];
        }
    }
    float4 bb = ((const float4*)b1)[l];
    f16x4 oA, oB;
    oA[0] = (_Float16)tanhf(accA.x + bb.x);
    oA[1] = (_Float16)tanhf(accA.y + bb.y);
    oA[2] = (_Float16)tanhf(accA.z + bb.z);
    oA[3] = (_Float16)tanhf(accA.w + bb.w);
    oB[0] = (_Float16)tanhf(accB.x + bb.x);
    oB[1] = (_Float16)tanhf(accB.y + bb.y);
    oB[2] = (_Float16)tanhf(accB.z + bb.z);
    oB[3] = (_Float16)tanhf(accB.w + bb.w);
    *(f16x4*)&hs[w * 2][l * 4]     = oA;
    *(f16x4*)&hs[w * 2 + 1][l * 4] = oB;
    __syncthreads();

    // GEMM23 phase: wave w -> s23 cols [16w, 16w+16), rows [brow0, brow0+16)
    int lr = l & 15, kg = l >> 4;
    int colbase = w * 16;
    f32x4 acc = (f32x4){0.f, 0.f, 0.f, 0.f};
    for (int ks = 0; ks < HH1; ks += 32) {
        int ko = ks + kg * 8;
        f16x8 a = *(const f16x8*)&hs[lr][ko];
        f16x8 bfrag = *(const f16x8*)&W23T[(size_t)(colbase + lr) * HH1 + ko];
        acc = __builtin_amdgcn_mfma_f32_16x16x32_f16(a, bfrag, acc, 0, 0, 0);
    }
#pragma unroll
    for (int r = 0; r < 4; r++)
        s23h[(size_t)(brow0 + kg * 4 + r) * 128 + colbase + lr] = (_Float16)acc[r];
}

// ---------------- K3: SpMM2+3 + reparameterization -> zout fp32, zh fp16 ----------------
__global__ __launch_bounds__(256) void k_spmm23v(const int* __restrict__ cnt,
                                                 const int2* __restrict__ epack,
                                                 const _Float16* __restrict__ s23,
                                                 const float* __restrict__ b2,
                                                 const float* __restrict__ b3,
                                                 const float* __restrict__ noise,
                                                 float* __restrict__ zout,
                                                 _Float16* __restrict__ zh) {
    int w = threadIdx.x >> 6, l = threadIdx.x & 63;
    int row = blockIdx.x * 4 + w;
    int s = row * RCAP, eend = s + cnt[row];
    float ax = 0.f, ay = 0.f;
    int i = s;
    for (; i + 4 <= eend; i += 4) {
        int2 p0 = epack[i];
        int2 p1 = epack[i + 1];
        int2 p2 = epack[i + 2];
        int2 p3 = epack[i + 3];
        f16x2 t0 = *(const f16x2*)&s23[(size_t)p0.x * 128 + l * 2];
        f16x2 t1 = *(const f16x2*)&s23[(size_t)p1.x * 128 + l * 2];
        f16x2 t2 = *(const f16x2*)&s23[(size_t)p2.x * 128 + l * 2];
        f16x2 t3 = *(const f16x2*)&s23[(size_t)p3.x * 128 + l * 2];
        float v0 = __int_as_float(p0.y), v1 = __int_as_float(p1.y);
        float v2 = __int_as_float(p2.y), v3 = __int_as_float(p3.y);
        ax += v0 * (float)t0[0] + v1 * (float)t1[0] + v2 * (float)t2[0] + v3 * (float)t3[0];
        ay += v0 * (float)t0[1] + v1 * (float)t1[1] + v2 * (float)t2[1] + v3 * (float)t3[1];
    }
    for (; i < eend; i++) {
        int2 p0 = epack[i];
        f16x2 t0 = *(const f16x2*)&s23[(size_t)p0.x * 128 + l * 2];
        float v0 = __int_as_float(p0.y);
        ax += v0 * (float)t0[0];
        ay += v0 * (float)t0[1];
    }
    float bx, by;
    if (l < 32) { bx = b2[2 * l]; by = b2[2 * l + 1]; }
    else        { bx = b3[2 * (l - 32)]; by = b3[2 * (l - 32) + 1]; }
    float t0 = tanhf(ax + bx);
    float t1 = tanhf(ay + by);
    float u0 = __shfl_xor(t0, 32, 64);   // mean lanes receive log_std partner
    float u1 = __shfl_xor(t1, 32, 64);
    if (l < 32) {
        float2 nz = ((const float2*)noise)[(size_t)row * 32 + l];
        float z0 = t0 + nz.x * __expf(u0);
        float z1 = t1 + nz.y * __expf(u1);
        ((float2*)zout)[(size_t)row * 32 + l] = make_float2(z0, z1);
        *(f16x2*)&zh[(size_t)row * 64 + l * 2] = (f16x2){(_Float16)z0, (_Float16)z1};
    }
}

// ---------------- K4: adj = sigmoid(z @ z^T), MFMA f16, transposed float4 stores ----------------
// adj symmetric: block (bi,bj) computes rows [bi*128+w*32,+32) x cols [bj*128,+128) and writes
// the TRANSPOSE (entry (p,q) written exactly once, by block bi=q/128, bj=p/128).
__global__ __launch_bounds__(256) void k_zzt_mfma(const _Float16* __restrict__ zh,
                                                  float* __restrict__ adj) {
    int bi = blockIdx.y, bj = blockIdx.x;
    int tid = threadIdx.x;
    int w = tid >> 6, l = tid & 63;
    int lr = l & 15, kg = l >> 4;
    const int i0 = bi * 128 + w * 32;
    const int j0 = bj * 128;

    f16x8 a[2][2];
#pragma unroll
    for (int mt = 0; mt < 2; mt++)
#pragma unroll
        for (int kk = 0; kk < 2; kk++)
            a[mt][kk] = *(const f16x8*)&zh[(size_t)(i0 + mt * 16 + lr) * 64 + kk * 32 + kg * 8];

    f32x4 acc[2][8];
#pragma unroll
    for (int mt = 0; mt < 2; mt++)
#pragma unroll
        for (int nt = 0; nt < 8; nt++)
            acc[mt][nt] = (f32x4){0.f, 0.f, 0.f, 0.f};

#pragma unroll
    for (int nt = 0; nt < 8; nt++) {
        f16x8 b0 = *(const f16x8*)&zh[(size_t)(j0 + nt * 16 + lr) * 64 + 0  + kg * 8];
        f16x8 b1 = *(const f16x8*)&zh[(size_t)(j0 + nt * 16 + lr) * 64 + 32 + kg * 8];
        acc[0][nt] = __builtin_amdgcn_mfma_f32_16x16x32_f16(a[0][0], b0, acc[0][nt], 0, 0, 0);
        acc[0][nt] = __builtin_amdgcn_mfma_f32_16x16x32_f16(a[0][1], b1, acc[0][nt], 0, 0, 0);
        acc[1][nt] = __builtin_amdgcn_mfma_f32_16x16x32_f16(a[1][0], b0, acc[1][nt], 0, 0, 0);
        acc[1][nt] = __builtin_amdgcn_mfma_f32_16x16x32_f16(a[1][1], b1, acc[1][nt], 0, 0, 0);
    }

#pragma unroll
    for (int nt = 0; nt < 8; nt++) {
#pragma unroll
        for (int mt = 0; mt < 2; mt++) {
            size_t orow = (size_t)(j0 + nt * 16 + lr);
            size_t ocol = (size_t)(i0 + mt * 16 + kg * 4);
            float4 o;
            o.x = fast_sigmoid(acc[mt][nt][0]);
            o.y = fast_sigmoid(acc[mt][nt][1]);
            o.z = fast_sigmoid(acc[mt][nt][2]);
            o.w = fast_sigmoid(acc[mt][nt][3]);
            *(float4*)&adj[orow * NN + ocol] = o;
        }
    }
}

extern "C" void kernel_launch(void* const* d_in, const int* in_sizes, int n_in,
                              void* d_out, int out_size, void* d_ws, size_t ws_size,
                              hipStream_t stream) {
    const int*   erow  = (const int*)d_in[0];
    const int*   ecol  = (const int*)d_in[1];
    const float* eval  = (const float*)d_in[2];
    const float* X     = (const float*)d_in[3];
    const float* W1    = (const float*)d_in[4];
    const float* b1    = (const float*)d_in[5];
    const float* W2    = (const float*)d_in[6];
    const float* b2    = (const float*)d_in[7];
    const float* W3    = (const float*)d_in[8];
    const float* b3    = (const float*)d_in[9];
    const float* noise = (const float*)d_in[10];

    float* adj  = (float*)d_out;
    float* zout = (float*)d_out + (size_t)NN * NN;

    // scratch in d_ws (~9.8 MB)
    char* ws = (char*)d_ws;
    int*  cnt       = (int*)(ws + 0);                    // 32 KiB
    int2* epack     = (int2*)(ws + 32768);               // 8 MiB (padded rows)
    _Float16* W1T   = (_Float16*)(ws + 8421376);         // 256 KiB
    _Float16* W23T  = (_Float16*)(ws + 8683520);         // 64 KiB
    _Float16* zh    = (_Float16*)(ws + 8749056);         // 1 MiB

    // large temporaries in the adj region of d_out (fully overwritten by k_zzt last)
    char* ob = (char*)d_out;
    _Float16* sup1h = (_Float16*)(ob + 0);               // 4 MiB
    _Float16* s23h  = (_Float16*)(ob + 4194304);         // 2 MiB

    k_init<<<192, 256, 0, stream>>>(W1, W2, W3, W1T, W23T, cnt);
    k_gemm1_scatter<<<512 + EE / 256, 256, 0, stream>>>(X, W1T, sup1h,
                                                        erow, ecol, eval, cnt, epack);
    k_spmm1_gemm23<<<512, 512, 0, stream>>>(cnt, epack, sup1h, b1, W23T, s23h);
    k_spmm23v<<<NN / 4, 256, 0, stream>>>(cnt, epack, s23h, b2, b3, noise, zout, zh);
    k_zzt_mfma<<<dim3(64, 64), 256, 0, stream>>>(zh, adj);
}

// Round 17
// 140.557 us; speedup vs baseline: 2.1360x; 1.0078x over previous
//
#include <hip/hip_runtime.h>
#include <math.h>

static constexpr int NN  = 8192;     // nodes
static constexpr int EE  = 262144;   // edges
static constexpr int IND = 512;      // input feature dim
static constexpr int HH1 = 256;
static constexpr int RCAP = 64;      // padded per-row edge capacity (deg~Bin(E,1/N): mean 32, max ~56)

typedef _Float16 f16x8  __attribute__((ext_vector_type(8)));
typedef _Float16 f16x4  __attribute__((ext_vector_type(4)));
typedef _Float16 f16x2  __attribute__((ext_vector_type(2)));
typedef float    f32x4  __attribute__((ext_vector_type(4)));

static __device__ __forceinline__ float fast_sigmoid(float x) {
    float e = __expf(-x);
    return __builtin_amdgcn_rcpf(1.f + e);
}

// ---------------- K0: init = zero cnt (blocks 0..31) + W1T (32..159) + W23T (160..191) ----------
__global__ __launch_bounds__(256) void k_init(const float* __restrict__ W1,
                                              const float* __restrict__ W2,
                                              const float* __restrict__ W3,
                                              _Float16* __restrict__ W1T,
                                              _Float16* __restrict__ W23T,
                                              int* __restrict__ cnt) {
    int b = blockIdx.x;
    if (b < 32) {
        cnt[b * 256 + threadIdx.x] = 0;
        return;
    }
    __shared__ float tile[32][33];
    int c = threadIdx.x & 31;
    int r0 = threadIdx.x >> 5;   // 0..7
    if (b < 160) {
        // W1 [512][256] -> W1T [256][512]
        int t = b - 32;
        int tk = t >> 3;   // 0..15
        int tn = t & 7;    // 0..7
#pragma unroll
        for (int i = 0; i < 4; i++) {
            int r = r0 * 4 + i;
            tile[r][c] = W1[(tk * 32 + r) * HH1 + tn * 32 + c];
        }
        __syncthreads();
#pragma unroll
        for (int i = 0; i < 4; i++) {
            int rr = r0 * 4 + i;
            W1T[(tn * 32 + rr) * IND + tk * 32 + c] = (_Float16)tile[c][rr];
        }
    } else {
        // [W2|W3] [256][64]x2 -> W23T [128][256]
        int t = b - 160;   // 0..31
        int tk = t >> 2;   // 0..7
        int tn = t & 3;    // tn<2 -> W2, else W3
        const float* Wsrc = (tn < 2) ? W2 : W3;
        int nc0 = (tn & 1) * 32;
#pragma unroll
        for (int i = 0; i < 4; i++) {
            int r = r0 * 4 + i;
            tile[r][c] = Wsrc[(tk * 32 + r) * 64 + nc0 + c];
        }
        __syncthreads();
#pragma unroll
        for (int i = 0; i < 4; i++) {
            int rr = r0 * 4 + i;
            W23T[(tn * 32 + rr) * HH1 + tk * 32 + c] = (_Float16)tile[c][rr];
        }
    }
}

// ---------------- K1: gemm1 (blocks 0..511) ∥ padded scatter (blocks 512..1535) ----------------
// gemm1: sup1h = fp16(X @ W1); X fp32 converted in-register. BM=32, BN=128, 4 waves 2x2.
__global__ __launch_bounds__(256) void k_gemm1_scatter(const float* __restrict__ X,
                                                       const _Float16* __restrict__ B,
                                                       _Float16* __restrict__ out,
                                                       const int* __restrict__ erow,
                                                       const int* __restrict__ ecol,
                                                       const float* __restrict__ eval,
                                                       int* __restrict__ cnt,
                                                       int2* __restrict__ epack) {
    int b = blockIdx.x;
    if (b >= 512) {
        int e = (b - 512) * 256 + threadIdx.x;
        int r = erow[e];
        int pos = atomicAdd(&cnt[r], 1);
        epack[(size_t)r * RCAP + pos] = make_int2(ecol[e], __float_as_int(eval[e]));
        return;
    }
    int bm = b >> 1, bn = b & 1;
    int w = threadIdx.x >> 6, l = threadIdx.x & 63;
    int wm = w >> 1, wn = w & 1;
    int lr = l & 15, kg = l >> 4;
    int row0 = bm * 32 + wm * 16;
    int col0 = bn * 128 + wn * 64;

    f32x4 acc[4];
#pragma unroll
    for (int nt = 0; nt < 4; nt++) acc[nt] = (f32x4){0.f, 0.f, 0.f, 0.f};

    for (int ks = 0; ks < IND; ks += 32) {
        int ko = ks + kg * 8;
        const float* xp = &X[(size_t)(row0 + lr) * IND + ko];
        float4 x0 = *(const float4*)xp;
        float4 x1 = *(const float4*)(xp + 4);
        f16x8 a = {(_Float16)x0.x, (_Float16)x0.y, (_Float16)x0.z, (_Float16)x0.w,
                   (_Float16)x1.x, (_Float16)x1.y, (_Float16)x1.z, (_Float16)x1.w};
        f16x8 bb[4];
#pragma unroll
        for (int nt = 0; nt < 4; nt++)
            bb[nt] = *(const f16x8*)&B[(size_t)(col0 + nt * 16 + lr) * IND + ko];
#pragma unroll
        for (int nt = 0; nt < 4; nt++)
            acc[nt] = __builtin_amdgcn_mfma_f32_16x16x32_f16(a, bb[nt], acc[nt], 0, 0, 0);
    }
#pragma unroll
    for (int nt = 0; nt < 4; nt++)
#pragma unroll
        for (int r = 0; r < 4; r++)
            out[(size_t)(row0 + kg * 4 + r) * HH1 + col0 + nt * 16 + lr] = (_Float16)acc[nt][r];
}

// ---------------- K2: fused SpMM1 + GEMM23, joint 2-row gather ----------
// 512 blocks x 512 threads (8 waves). Wave w aggregates rows 2w and 2w+1 together (8 gathers
// in flight), tanh -> LDS [16][264] fp16, then each wave does 8 MFMAs for a 16-col s23 slice.
__global__ __launch_bounds__(512) void k_spmm1_gemm23(const int* __restrict__ cnt,
                                                      const int2* __restrict__ epack,
                                                      const _Float16* __restrict__ sup,
                                                      const float* __restrict__ b1,
                                                      const _Float16* __restrict__ W23T,
                                                      _Float16* __restrict__ s23h) {
    __shared__ _Float16 hs[16][264];
    int w = threadIdx.x >> 6, l = threadIdx.x & 63;
    int brow0 = blockIdx.x * 16;

    int rowA = brow0 + w * 2;
    int rowB = rowA + 1;
    int sA = rowA * RCAP, lenA = cnt[rowA];
    int sB = rowB * RCAP, lenB = cnt[rowB];
    float4 accA = make_float4(0.f, 0.f, 0.f, 0.f);
    float4 accB = make_float4(0.f, 0.f, 0.f, 0.f);

    int joint = (lenA < lenB) ? lenA : lenB;
    int i = 0;
    for (; i + 4 <= joint; i += 4) {
        int2 a0 = epack[sA + i],     a1 = epack[sA + i + 1];
        int2 a2 = epack[sA + i + 2], a3 = epack[sA + i + 3];
        int2 c0 = epack[sB + i],     c1 = epack[sB + i + 1];
        int2 c2 = epack[sB + i + 2], c3 = epack[sB + i + 3];
        f16x4 ta0 = *(const f16x4*)&sup[(size_t)a0.x * HH1 + l * 4];
        f16x4 ta1 = *(const f16x4*)&sup[(size_t)a1.x * HH1 + l * 4];
        f16x4 ta2 = *(const f16x4*)&sup[(size_t)a2.x * HH1 + l * 4];
        f16x4 ta3 = *(const f16x4*)&sup[(size_t)a3.x * HH1 + l * 4];
        f16x4 tb0 = *(const f16x4*)&sup[(size_t)c0.x * HH1 + l * 4];
        f16x4 tb1 = *(const f16x4*)&sup[(size_t)c1.x * HH1 + l * 4];
        f16x4 tb2 = *(const f16x4*)&sup[(size_t)c2.x * HH1 + l * 4];
        f16x4 tb3 = *(const f16x4*)&sup[(size_t)c3.x * HH1 + l * 4];
        float va0 = __int_as_float(a0.y), va1 = __int_as_float(a1.y);
        float va2 = __int_as_float(a2.y), va3 = __int_as_float(a3.y);
        float vb0 = __int_as_float(c0.y), vb1 = __int_as_float(c1.y);
        float vb2 = __int_as_float(c2.y), vb3 = __int_as_float(c3.y);
        accA.x += va0 * (float)ta0[0] + va1 * (float)ta1[0] + va2 * (float)ta2[0] + va3 * (float)ta3[0];
        accA.y += va0 * (float)ta0[1] + va1 * (float)ta1[1] + va2 * (float)ta2[1] + va3 * (float)ta3[1];
        accA.z += va0 * (float)ta0[2] + va1 * (float)ta1[2] + va2 * (float)ta2[2] + va3 * (float)ta3[2];
        accA.w += va0 * (float)ta0[3] + va1 * (float)ta1[3] + va2 * (float)ta2[3] + va3 * (float)ta3[3];
        accB.x += vb0 * (float)tb0[0] + vb1 * (float)tb1[0] + vb2 * (float)tb2[0] + vb3 * (float)tb3[0];
        accB.y += vb0 * (float)tb0[1] + vb1 * (float)tb1[1] + vb2 * (float)tb2[1] + vb3 * (float)tb3[1];
        accB.z += vb0 * (float)tb0[2] + vb1 * (float)tb1[2] + vb2 * (float)tb2[2] + vb3 * (float)tb3[2];
        accB.w += vb0 * (float)tb0[3] + vb1 * (float)tb1[3] + vb2 * (float)tb2[3] + vb3 * (float)tb3[3];
    }
    // row A tail
    {
        int ia = i;
        for (; ia + 4 <= lenA; ia += 4) {
            int2 a0 = epack[sA + ia],     a1 = epack[sA + ia + 1];
            int2 a2 = epack[sA + ia + 2], a3 = epack[sA + ia + 3];
            f16x4 t0 = *(const f16x4*)&sup[(size_t)a0.x * HH1 + l * 4];
            f16x4 t1 = *(const f16x4*)&sup[(size_t)a1.x * HH1 + l * 4];
            f16x4 t2 = *(const f16x4*)&sup[(size_t)a2.x * HH1 + l * 4];
            f16x4 t3 = *(const f16x4*)&sup[(size_t)a3.x * HH1 + l * 4];
            float v0 = __int_as_float(a0.y), v1 = __int_as_float(a1.y);
            float v2 = __int_as_float(a2.y), v3 = __int_as_float(a3.y);
            accA.x += v0 * (float)t0[0] + v1 * (float)t1[0] + v2 * (float)t2[0] + v3 * (float)t3[0];
            accA.y += v0 * (float)t0[1] + v1 * (float)t1[1] + v2 * (float)t2[1] + v3 * (float)t3[1];
            accA.z += v0 * (float)t0[2] + v1 * (float)t1[2] + v2 * (float)t2[2] + v3 * (float)t3[2];
            accA.w += v0 * (float)t0[3] + v1 * (float)t1[3] + v2 * (float)t2[3] + v3 * (float)t3[3];
        }
        for (; ia < lenA; ia++) {
            int2 p0 = epack[sA + ia];
            f16x4 t0 = *(const f16x4*)&sup[(size_t)p0.x * HH1 + l * 4];
            float v0 = __int_as_float(p0.y);
            accA.x += v0 * (float)t0[0];
            accA.y += v0 * (float)t0[1];
            accA.z += v0 * (float)t0[2];
            accA.w += v0 * (float)t0[3];
        }
    }
    // row B tail
    {
        int ib = i;
        for (; ib + 4 <= lenB; ib += 4) {
            int2 a0 = epack[sB + ib],     a1 = epack[sB + ib + 1];
            int2 a2 = epack[sB + ib + 2], a3 = epack[sB + ib + 3];
            f16x4 t0 = *(const f16x4*)&sup[(size_t)a0.x * HH1 + l * 4];
            f16x4 t1 = *(const f16x4*)&sup[(size_t)a1.x * HH1 + l * 4];
            f16x4 t2 = *(const f16x4*)&sup[(size_t)a2.x * HH1 + l * 4];
            f16x4 t3 = *(const f16x4*)&sup[(size_t)a3.x * HH1 + l * 4];
            float v0 = __int_as_float(a0.y), v1 = __int_as_float(a1.y);
            float v2 = __int_as_float(a2.y), v3 = __int_as_float(a3.y);
            accB.x += v0 * (float)t0[0] + v1 * (float)t1[0] + v2 * (float)t2[0] + v3 * (float)t3[0];
            accB.y += v0 * (float)t0[1] + v1 * (float)t1[1] + v2 * (float)t2[1] + v3 * (float)t3[1];
            accB.z += v0 * (float)t0[2] + v1 * (float)t1[2] + v2 * (float)t2[2] + v3 * (float)t3[2];
            accB.w += v0 * (float)t0[3] + v1 * (float)t1[3] + v2 * (float)t2[3] + v3 * (float)t3[3];
        }
        for (; ib < lenB; ib++) {
            int2 p0 = epack[sB + ib];
            f16x4 t0 = *(const f16x4*)&sup[(size_t)p0.x * HH1 + l * 4];
            float v0 = __int_as_float(p0.y);
            accB.x += v0 * (float)t0[0];
            accB.y += v0 * (float)t0[1];
            accB.z += v0 * (float)t0[2];
            accB.w += v0 * (float)t0[3];
        }
    }
    float4 bb = ((const float4*)b1)[l];
    f16x4 oA, oB;
    oA[0] = (_Float16)tanhf(accA.x + bb.x);
    oA[1] = (_Float16)tanhf(accA.y + bb.y);
    oA[2] = (_Float16)tanhf(accA.z + bb.z);
    oA[3] = (_Float16)tanhf(accA.w + bb.w);
    oB[0] = (_Float16)tanhf(accB.x + bb.x);
    oB[1] = (_Float16)tanhf(accB.y + bb.y);
    oB[2] = (_Float16)tanhf(accB.z + bb.z);
    oB[3] = (_Float16)tanhf(accB.w + bb.w);
    *(f16x4*)&hs[w * 2][l * 4]     = oA;
    *(f16x4*)&hs[w * 2 + 1][l * 4] = oB;
    __syncthreads();

    // GEMM23 phase: wave w -> s23 cols [16w, 16w+16), rows [brow0, brow0+16)
    int lr = l & 15, kg = l >> 4;
    int colbase = w * 16;
    f32x4 acc = (f32x4){0.f, 0.f, 0.f, 0.f};
    for (int ks = 0; ks < HH1; ks += 32) {
        int ko = ks + kg * 8;
        f16x8 a = *(const f16x8*)&hs[lr][ko];
        f16x8 bfrag = *(const f16x8*)&W23T[(size_t)(colbase + lr) * HH1 + ko];
        acc = __builtin_amdgcn_mfma_f32_16x16x32_f16(a, bfrag, acc, 0, 0, 0);
    }
#pragma unroll
    for (int r = 0; r < 4; r++)
        s23h[(size_t)(brow0 + kg * 4 + r) * 128 + colbase + lr] = (_Float16)acc[r];
}

// ---------------- K3: SpMM2+3 + reparameterization -> zout fp32, zh fp16 ----------------
__global__ __launch_bounds__(256) void k_spmm23v(const int* __restrict__ cnt,
                                                 const int2* __restrict__ epack,
                                                 const _Float16* __restrict__ s23,
                                                 const float* __restrict__ b2,
                                                 const float* __restrict__ b3,
                                                 const float* __restrict__ noise,
                                                 float* __restrict__ zout,
                                                 _Float16* __restrict__ zh) {
    int w = threadIdx.x >> 6, l = threadIdx.x & 63;
    int row = blockIdx.x * 4 + w;
    int s = row * RCAP, eend = s + cnt[row];
    float ax = 0.f, ay = 0.f;
    int i = s;
    for (; i + 4 <= eend; i += 4) {
        int2 p0 = epack[i];
        int2 p1 = epack[i + 1];
        int2 p2 = epack[i + 2];
        int2 p3 = epack[i + 3];
        f16x2 t0 = *(const f16x2*)&s23[(size_t)p0.x * 128 + l * 2];
        f16x2 t1 = *(const f16x2*)&s23[(size_t)p1.x * 128 + l * 2];
        f16x2 t2 = *(const f16x2*)&s23[(size_t)p2.x * 128 + l * 2];
        f16x2 t3 = *(const f16x2*)&s23[(size_t)p3.x * 128 + l * 2];
        float v0 = __int_as_float(p0.y), v1 = __int_as_float(p1.y);
        float v2 = __int_as_float(p2.y), v3 = __int_as_float(p3.y);
        ax += v0 * (float)t0[0] + v1 * (float)t1[0] + v2 * (float)t2[0] + v3 * (float)t3[0];
        ay += v0 * (float)t0[1] + v1 * (float)t1[1] + v2 * (float)t2[1] + v3 * (float)t3[1];
    }
    for (; i < eend; i++) {
        int2 p0 = epack[i];
        f16x2 t0 = *(const f16x2*)&s23[(size_t)p0.x * 128 + l * 2];
        float v0 = __int_as_float(p0.y);
        ax += v0 * (float)t0[0];
        ay += v0 * (float)t0[1];
    }
    float bx, by;
    if (l < 32) { bx = b2[2 * l]; by = b2[2 * l + 1]; }
    else        { bx = b3[2 * (l - 32)]; by = b3[2 * (l - 32) + 1]; }
    float t0 = tanhf(ax + bx);
    float t1 = tanhf(ay + by);
    float u0 = __shfl_xor(t0, 32, 64);   // mean lanes receive log_std partner
    float u1 = __shfl_xor(t1, 32, 64);
    if (l < 32) {
        float2 nz = ((const float2*)noise)[(size_t)row * 32 + l];
        float z0 = t0 + nz.x * __expf(u0);
        float z1 = t1 + nz.y * __expf(u1);
        ((float2*)zout)[(size_t)row * 32 + l] = make_float2(z0, z1);
        *(f16x2*)&zh[(size_t)row * 64 + l * 2] = (f16x2){(_Float16)z0, (_Float16)z1};
    }
}

// ---------------- K4: adj = sigmoid(z @ z^T), MFMA f16, transposed float4 stores ----------------
// adj symmetric: block (bi,bj) computes rows [bi*128+w*32,+32) x cols [bj*128,+128) and writes
// the TRANSPOSE (entry (p,q) written exactly once, by block bi=q/128, bj=p/128).
__global__ __launch_bounds__(256) void k_zzt_mfma(const _Float16* __restrict__ zh,
                                                  float* __restrict__ adj) {
    int bi = blockIdx.y, bj = blockIdx.x;
    int tid = threadIdx.x;
    int w = tid >> 6, l = tid & 63;
    int lr = l & 15, kg = l >> 4;
    const int i0 = bi * 128 + w * 32;
    const int j0 = bj * 128;

    f16x8 a[2][2];
#pragma unroll
    for (int mt = 0; mt < 2; mt++)
#pragma unroll
        for (int kk = 0; kk < 2; kk++)
            a[mt][kk] = *(const f16x8*)&zh[(size_t)(i0 + mt * 16 + lr) * 64 + kk * 32 + kg * 8];

    f32x4 acc[2][8];
#pragma unroll
    for (int mt = 0; mt < 2; mt++)
#pragma unroll
        for (int nt = 0; nt < 8; nt++)
            acc[mt][nt] = (f32x4){0.f, 0.f, 0.f, 0.f};

#pragma unroll
    for (int nt = 0; nt < 8; nt++) {
        f16x8 b0 = *(const f16x8*)&zh[(size_t)(j0 + nt * 16 + lr) * 64 + 0  + kg * 8];
        f16x8 b1 = *(const f16x8*)&zh[(size_t)(j0 + nt * 16 + lr) * 64 + 32 + kg * 8];
        acc[0][nt] = __builtin_amdgcn_mfma_f32_16x16x32_f16(a[0][0], b0, acc[0][nt], 0, 0, 0);
        acc[0][nt] = __builtin_amdgcn_mfma_f32_16x16x32_f16(a[0][1], b1, acc[0][nt], 0, 0, 0);
        acc[1][nt] = __builtin_amdgcn_mfma_f32_16x16x32_f16(a[1][0], b0, acc[1][nt], 0, 0, 0);
        acc[1][nt] = __builtin_amdgcn_mfma_f32_16x16x32_f16(a[1][1], b1, acc[1][nt], 0, 0, 0);
    }

#pragma unroll
    for (int nt = 0; nt < 8; nt++) {
#pragma unroll
        for (int mt = 0; mt < 2; mt++) {
            size_t orow = (size_t)(j0 + nt * 16 + lr);
            size_t ocol = (size_t)(i0 + mt * 16 + kg * 4);
            float4 o;
            o.x = fast_sigmoid(acc[mt][nt][0]);
            o.y = fast_sigmoid(acc[mt][nt][1]);
            o.z = fast_sigmoid(acc[mt][nt][2]);
            o.w = fast_sigmoid(acc[mt][nt][3]);
            *(float4*)&adj[orow * NN + ocol] = o;
        }
    }
}

extern "C" void kernel_launch(void* const* d_in, const int* in_sizes, int n_in,
                              void* d_out, int out_size, void* d_ws, size_t ws_size,
                              hipStream_t stream) {
    const int*   erow  = (const int*)d_in[0];
    const int*   ecol  = (const int*)d_in[1];
    const float* eval  = (const float*)d_in[2];
    const float* X     = (const float*)d_in[3];
    const float* W1    = (const float*)d_in[4];
    const float* b1    = (const float*)d_in[5];
    const float* W2    = (const float*)d_in[6];
    const float* b2    = (const float*)d_in[7];
    const float* W3    = (const float*)d_in[8];
    const float* b3    = (const float*)d_in[9];
    const float* noise = (const float*)d_in[10];

    float* adj  = (float*)d_out;
    float* zout = (float*)d_out + (size_t)NN * NN;

    // scratch in d_ws (~5.8 MB)
    char* ws = (char*)d_ws;
    int*  cnt       = (int*)(ws + 0);                    // 32 KiB
    int2* epack     = (int2*)(ws + 32768);               // 8192*64*8 = 4 MiB (padded rows)
    _Float16* W1T   = (_Float16*)(ws + 4227072);         // 256 KiB
    _Float16* W23T  = (_Float16*)(ws + 4489216);         // 64 KiB
    _Float16* zh    = (_Float16*)(ws + 4554752);         // 1 MiB

    // large temporaries in the adj region of d_out (fully overwritten by k_zzt last)
    char* ob = (char*)d_out;
    _Float16* sup1h = (_Float16*)(ob + 0);               // 4 MiB
    _Float16* s23h  = (_Float16*)(ob + 4194304);         // 2 MiB

    k_init<<<192, 256, 0, stream>>>(W1, W2, W3, W1T, W23T, cnt);
    k_gemm1_scatter<<<512 + EE / 256, 256, 0, stream>>>(X, W1T, sup1h,
                                                        erow, ecol, eval, cnt, epack);
    k_spmm1_gemm23<<<512, 512, 0, stream>>>(cnt, epack, sup1h, b1, W23T, s23h);
    k_spmm23v<<<NN / 4, 256, 0, stream>>>(cnt, epack, s23h, b2, b3, noise, zout, zh);
    k_zzt_mfma<<<dim3(64, 64), 256, 0, stream>>>(zh, adj);
}